// Round 1
// baseline (14964.273 us; speedup 1.0000x reference)
//
#include <hip/hip_runtime.h>

// ============================================================================
// Siamese 3-layer masked LSTM (B=32, 2 sides, T=1024, F=128, H=256)
// Architecture:
//   prep:   mask[64][1024] (any feature != 0), x -> bf16, zero sync counters
//   scan<DK> x3 (layer-sequential):
//     grid = 16 blocks = 4 groups (16 seqs) x 4 N-slices (64 hidden units each)
//     per block: W/U column slice ((DK*32+256) x 256 cols) preloaded as bf16
//                MFMA fragments in registers (~256 VGPRs, launch_bounds(256,1))
//     per step:  z = [x_t | h] @ [W;U] + b   via mfma_f32_16x16x32_bf16
//                gates fp32, mask-carry h/c, h-slice exchanged between the 4
//                sibling blocks through agent-scope atomics + counter barrier
//                (double-buffered by step parity)
//   final:  dist = ||h1-h2||, sigmoid(dist*w+b)
// Workspace: ~81 MB
// ============================================================================

typedef __attribute__((ext_vector_type(8))) short bf16x8;
typedef __attribute__((ext_vector_type(4))) float f32x4;

__device__ __forceinline__ unsigned short f2bf(float f){
    unsigned u = __float_as_uint(f);
    u += 0x7FFFu + ((u >> 16) & 1u);        // round-to-nearest-even
    return (unsigned short)(u >> 16);
}
__device__ __forceinline__ float fsig(float x){ return 1.0f / (1.0f + __expf(-x)); }
__device__ __forceinline__ float ftanh(float x){
    float e = __expf(-2.0f * fabsf(x));     // e in (0,1], no overflow
    float t = (1.0f - e) / (1.0f + e);
    return copysignf(t, x);
}

// ---------------------------------------------------------------------------
// prep: mask + bf16 cast of inputs + zero the sync counters
// grid (64 seq, 16 chunks) x 64 threads; each block does 64 timesteps
// ---------------------------------------------------------------------------
__global__ void prep_kernel(const float* __restrict__ x, unsigned int* __restrict__ xb,
                            float* __restrict__ mask, int* __restrict__ counters){
    const int s = blockIdx.x;     // sequence 0..63  (= b*2 + side)
    const int c = blockIdx.y;     // chunk 0..15
    const int l = threadIdx.x;    // 0..63
    if (s == 0 && c == 0 && l < 64) counters[l] = 0;   // replay-safe re-zero
    const float* xs = x + ((size_t)s * 1024 + (size_t)c * 64) * 128;
    for (int tt = 0; tt < 64; ++tt){
        const float2 v = *(const float2*)(xs + (size_t)tt * 128 + 2 * l);
        bool nz = (v.x != 0.0f) || (v.y != 0.0f);
        unsigned long long b = __ballot(nz);           // 64-bit on CDNA
        int t = c * 64 + tt;
        if (l == 0) mask[s * 1024 + t] = b ? 1.0f : 0.0f;
        unsigned int p = (unsigned)f2bf(v.x) | ((unsigned)f2bf(v.y) << 16);
        xb[((size_t)s * 1024 + t) * 64 + l] = p;       // [seq][t][128] bf16
    }
}

// ---------------------------------------------------------------------------
// scan<DK>: one LSTM layer. DK = K-tiles of the input part (4 -> D=128, 8 -> 256)
// ---------------------------------------------------------------------------
template<int DK>
__global__ __launch_bounds__(256, 1) void scan_kernel(
    const unsigned short* __restrict__ xin,   // [64][1024][DK*32] bf16
    const float* __restrict__ W, const float* __restrict__ U,
    const float* __restrict__ Bv,             // bias [1024]
    const float* __restrict__ mask,           // [64][1024]
    unsigned int* __restrict__ hseqOut,       // [64][1024][128] u32(bf16x2) or null
    float* __restrict__ hfinal,               // [64][256] or null
    unsigned int* __restrict__ hx,            // [2][4][16][128] u32 exchange buf
    int* __restrict__ counters)               // [4] per-group barrier counters
{
    constexpr int KT = DK + 8;
    static_assert(KT <= 16, "");
    const int bid = blockIdx.x;
    const int g = bid >> 2, n = bid & 3;      // group, N-slice
    const int tid  = threadIdx.x;
    const int w    = tid >> 6;                // wave 0..3
    const int lane = tid & 63;
    const int l15  = lane & 15, lk = lane >> 4;
    const int up   = lane & 7,  s2 = lane >> 3;

    __shared__ unsigned short hA[4096];       // [16 seq][256] bf16, 16B-chunk XOR swizzle
    __shared__ float zw[4][16][68];           // per-wave z slice [seq][64 cols + pad]
    __shared__ int sgl;

    if (tid == 0) sgl = 0;
    __syncthreads();
    // group length = max over 16 seqs of (last masked t + 1)
    int mymax = 0;
    for (int tt = tid; tt < 1024; tt += 256){
        bool any = false;
        for (int s = 0; s < 16; ++s) any |= (mask[((g * 16 + s) << 10) + tt] != 0.0f);
        if (any) mymax = tt + 1;              // tt ascending -> last assignment is max
    }
    atomicMax(&sgl, mymax);
    for (int i = tid; i < 4096; i += 256) hA[i] = 0;   // h(0) = 0

    // ---- gate columns, bias, register-resident B fragments -----------------
    // local col lc = hid_local*4 + gate(i,f,g,o); global col = gate*256 + n*64 + hid_local
    float bfr[4];
    int gcol[4];
    #pragma unroll
    for (int nt = 0; nt < 4; ++nt){
        int lc = w * 64 + nt * 16 + l15;
        gcol[nt] = (lc & 3) * 256 + n * 64 + (lc >> 2);
        bfr[nt] = Bv[gcol[nt]];
    }
    bf16x8 Bf[KT][4];                          // ~256 VGPRs (KT=16)
    #pragma unroll
    for (int kt = 0; kt < KT; ++kt){
        const float* src = (kt < DK) ? (W + (size_t)(kt * 32 + lk * 8) * 1024)
                                     : (U + (size_t)((kt - DK) * 32 + lk * 8) * 1024);
        #pragma unroll
        for (int nt = 0; nt < 4; ++nt){
            bf16x8 v;
            #pragma unroll
            for (int j = 0; j < 8; ++j) v[j] = (short)f2bf(src[(size_t)j * 1024 + gcol[nt]]);
            Bf[kt][nt] = v;
        }
    }
    __syncthreads();
    const int gl = sgl;
    int* cnt = counters + g;

    // per-thread LSTM state: (seq s2, hid ul), (s2, ul+1), (s2+8, ul), (s2+8, ul+1)
    float c00 = 0, c01 = 0, c10 = 0, c11 = 0;
    float h00 = 0, h01 = 0, h10 = 0, h11 = 0;
    const int myseq0 = g * 16 + s2, myseq1 = g * 16 + s2 + 8;
    const int hcol = n * 32 + w * 8 + up;      // packed u32 column of our hid pair

    for (int t = 0; t < gl; ++t){
        f32x4 acc[4];
        #pragma unroll
        for (int nt = 0; nt < 4; ++nt) acc[nt] = (f32x4){bfr[nt], bfr[nt], bfr[nt], bfr[nt]};

        // ---- x part (independent of h -> overlaps the barrier wait) --------
        const unsigned short* xrow =
            xin + ((size_t)(g * 16 + l15) * 1024 + t) * (DK * 32) + lk * 8;
        #pragma unroll
        for (int kt = 0; kt < DK; ++kt){
            bf16x8 a = *(const bf16x8*)(xrow + kt * 32);
            #pragma unroll
            for (int nt = 0; nt < 4; ++nt)
                acc[nt] = __builtin_amdgcn_mfma_f32_16x16x32_bf16(a, Bf[kt][nt], acc[nt], 0, 0, 0);
        }

        // ---- wait for h(t-1) from siblings, collect into LDS ----------------
        if (t > 0){
            if (tid == 0){
                while (__hip_atomic_load(cnt, __ATOMIC_ACQUIRE, __HIP_MEMORY_SCOPE_AGENT) < 4 * t)
                    __builtin_amdgcn_s_sleep(1);
            }
            __syncthreads();
            unsigned int* hxg = hx + (((t - 1) & 1) * 4 + g) * 2048;
            unsigned long long v0, v1, v2, v3;
            unsigned long long* hp = (unsigned long long*)hxg + (size_t)tid * 4;
            v0 = __hip_atomic_load(hp + 0, __ATOMIC_RELAXED, __HIP_MEMORY_SCOPE_AGENT);
            v1 = __hip_atomic_load(hp + 1, __ATOMIC_RELAXED, __HIP_MEMORY_SCOPE_AGENT);
            v2 = __hip_atomic_load(hp + 2, __ATOMIC_RELAXED, __HIP_MEMORY_SCOPE_AGENT);
            v3 = __hip_atomic_load(hp + 3, __ATOMIC_RELAXED, __HIP_MEMORY_SCOPE_AGENT);
            int si = tid >> 4;
            int cb = (tid & 15) * 32;                       // byte offset in 512B row
            int b0 = (si << 9) + ((cb)      ^ ((si & 7) << 4));
            int b1 = (si << 9) + ((cb + 16) ^ ((si & 7) << 4));
            *(unsigned long long*)((char*)hA + b0)      = v0;
            *(unsigned long long*)((char*)hA + b0 + 8)  = v1;
            *(unsigned long long*)((char*)hA + b1)      = v2;
            *(unsigned long long*)((char*)hA + b1 + 8)  = v3;
            __syncthreads();
        }

        // ---- h part ---------------------------------------------------------
        #pragma unroll
        for (int kh = 0; kh < 8; ++kh){
            int byteOff = (l15 << 9) + ((kh * 64 + lk * 16) ^ ((l15 & 7) << 4));
            bf16x8 a = *(const bf16x8*)((const char*)hA + byteOff);
            #pragma unroll
            for (int nt = 0; nt < 4; ++nt)
                acc[nt] = __builtin_amdgcn_mfma_f32_16x16x32_bf16(a, Bf[DK + kh][nt], acc[nt], 0, 0, 0);
        }

        // ---- z -> LDS (wave-private region), then gates ---------------------
        #pragma unroll
        for (int nt = 0; nt < 4; ++nt){
            #pragma unroll
            for (int r = 0; r < 4; ++r)
                zw[w][lk * 4 + r][nt * 16 + l15] = acc[nt][r];   // row = seq, col = lc
        }
        asm volatile("s_waitcnt lgkmcnt(0)" ::: "memory");
        __builtin_amdgcn_sched_barrier(0);

        float m0 = mask[(myseq0 << 10) + t];
        float m1 = mask[(myseq1 << 10) + t];
        const float* z0 = &zw[w][s2][up * 8];
        const float* z1 = &zw[w][s2 + 8][up * 8];
        float cn, hn;
        cn = fsig(z0[1]) * c00 + fsig(z0[0]) * ftanh(z0[2]); hn = fsig(z0[3]) * ftanh(cn);
        if (m0 != 0.0f){ c00 = cn; h00 = hn; }
        cn = fsig(z0[5]) * c01 + fsig(z0[4]) * ftanh(z0[6]); hn = fsig(z0[7]) * ftanh(cn);
        if (m0 != 0.0f){ c01 = cn; h01 = hn; }
        cn = fsig(z1[1]) * c10 + fsig(z1[0]) * ftanh(z1[2]); hn = fsig(z1[3]) * ftanh(cn);
        if (m1 != 0.0f){ c10 = cn; h10 = hn; }
        cn = fsig(z1[5]) * c11 + fsig(z1[4]) * ftanh(z1[6]); hn = fsig(z1[7]) * ftanh(cn);
        if (m1 != 0.0f){ c11 = cn; h11 = hn; }

        // ---- publish --------------------------------------------------------
        unsigned int p0 = (unsigned)f2bf(h00) | ((unsigned)f2bf(h01) << 16);
        unsigned int p1 = (unsigned)f2bf(h10) | ((unsigned)f2bf(h11) << 16);
        if (hseqOut){
            hseqOut[((size_t)myseq0 * 1024 + t) * 128 + hcol] = p0;
            hseqOut[((size_t)myseq1 * 1024 + t) * 128 + hcol] = p1;
        }
        if (t + 1 < gl){
            unsigned int* hxg = hx + ((t & 1) * 4 + g) * 2048;
            __hip_atomic_store(hxg + s2 * 128 + hcol,       p0, __ATOMIC_RELAXED, __HIP_MEMORY_SCOPE_AGENT);
            __hip_atomic_store(hxg + (s2 + 8) * 128 + hcol, p1, __ATOMIC_RELAXED, __HIP_MEMORY_SCOPE_AGENT);
            __threadfence();
            __syncthreads();   // all publishes drained (vmcnt(0)) before the add
            if (tid == 0)
                __hip_atomic_fetch_add(cnt, 1, __ATOMIC_RELEASE, __HIP_MEMORY_SCOPE_AGENT);
        }
    }

    if (hfinal){
        const int colb = n * 64 + w * 16 + up * 2;
        hfinal[(size_t)myseq0 * 256 + colb]     = h00;
        hfinal[(size_t)myseq0 * 256 + colb + 1] = h01;
        hfinal[(size_t)myseq1 * 256 + colb]     = h10;
        hfinal[(size_t)myseq1 * 256 + colb + 1] = h11;
    }
}

// ---------------------------------------------------------------------------
// final: dist = ||h1 - h2||, out = sigmoid(dist*w + b)
// ---------------------------------------------------------------------------
__global__ void final_kernel(const float* __restrict__ hfinal, const float* __restrict__ dw,
                             const float* __restrict__ db, float* __restrict__ out){
    const int b = threadIdx.x >> 3, j = threadIdx.x & 7;   // 32 batches x 8 lanes
    const float* ha = hfinal + (size_t)(2 * b) * 256;
    const float* hb = ha + 256;
    float s = 0.0f;
    for (int d = j; d < 256; d += 8){ float df = ha[d] - hb[d]; s += df * df; }
    #pragma unroll
    for (int off = 4; off; off >>= 1) s += __shfl_xor(s, off, 8);
    if (j == 0){
        float dist = sqrtf(s);
        dist = fminf(fmaxf(dist, 1e-7f), 1e7f);
        out[b] = fsig(dist * dw[0] + db[0]);
    }
}

// ---------------------------------------------------------------------------
extern "C" void kernel_launch(void* const* d_in, const int* in_sizes, int n_in,
                              void* d_out, int out_size, void* d_ws, size_t ws_size,
                              hipStream_t stream){
    const float* x  = (const float*)d_in[0];
    const float* W0 = (const float*)d_in[1];
    const float* U0 = (const float*)d_in[2];
    const float* b0 = (const float*)d_in[3];
    const float* W1 = (const float*)d_in[4];
    const float* U1 = (const float*)d_in[5];
    const float* b1 = (const float*)d_in[6];
    const float* W2 = (const float*)d_in[7];
    const float* U2 = (const float*)d_in[8];
    const float* b2 = (const float*)d_in[9];
    const float* dw = (const float*)d_in[10];
    const float* db = (const float*)d_in[11];

    // workspace layout (~81 MB)
    char* ws = (char*)d_ws;
    unsigned int*   xb     = (unsigned int*)(ws);                    // 16 MB bf16 input
    unsigned short* hseqA  = (unsigned short*)(ws + 16777216ull);    // 32 MB
    unsigned short* hseqB  = (unsigned short*)(ws + 50331648ull);    // 32 MB
    float*          mask   = (float*)(ws + 83886080ull);             // 256 KB
    unsigned int*   hx0    = (unsigned int*)(ws + 84148224ull);      // 64 KB each
    unsigned int*   hx1    = hx0 + 16384;
    unsigned int*   hx2    = hx1 + 16384;
    int*            cnts   = (int*)(ws + 84344832ull);               // 64 ints
    float*          hfinal = (float*)(ws + 84345088ull);             // 64 KB
    float*          out    = (float*)d_out;

    prep_kernel<<<dim3(64, 16), 64, 0, stream>>>(x, xb, mask, cnts);
    scan_kernel<4><<<16, 256, 0, stream>>>((const unsigned short*)xb, W0, U0, b0, mask,
                                           (unsigned int*)hseqA, nullptr, hx0, cnts + 0);
    scan_kernel<8><<<16, 256, 0, stream>>>(hseqA, W1, U1, b1, mask,
                                           (unsigned int*)hseqB, nullptr, hx1, cnts + 4);
    scan_kernel<8><<<16, 256, 0, stream>>>(hseqB, W2, U2, b2, mask,
                                           nullptr, hfinal, hx2, cnts + 8);
    final_kernel<<<1, 256, 0, stream>>>(hfinal, dw, db, out);
}

// Round 2
// 6962.046 us; speedup vs baseline: 2.1494x; 2.1494x over previous
//
#include <hip/hip_runtime.h>

// ============================================================================
// Siamese 3-layer masked LSTM (B=32, 2 sides, T=1024, F=128, H=256)
// Fused pipelined design:
//   prep:  bit-mask mb[64][32], x -> bf16 xb, zero flags
//   scan3: ONE launch, 48 blocks = 3 layers x 4 groups x 4 N-slices.
//          Layer l step t consumes layer l-1 step t (1-step pipeline lag) and
//          its own siblings' h(t-1). All cross-block data moves through
//          RELAXED agent-scope atomics (sc1, coherence-point, NO cache
//          invalidates); per-step readiness via per-block flag stores
//          (RELEASE after __syncthreads drains the data stores).
//          Weights live in ~256 registers/thread as MFMA B-fragments.
//   final: dist = ||h1-h2||, sigmoid(dist*w+b)
// Workspace ~80.3 MB.
// ============================================================================

typedef __attribute__((ext_vector_type(8))) short bf16x8;
typedef __attribute__((ext_vector_type(4))) float f32x4;
typedef unsigned long long ull;

__device__ __forceinline__ unsigned short f2bf(float f){
    unsigned u = __float_as_uint(f);
    u += 0x7FFFu + ((u >> 16) & 1u);        // round-to-nearest-even
    return (unsigned short)(u >> 16);
}
__device__ __forceinline__ float fsig(float x){ return 1.0f / (1.0f + __expf(-x)); }
__device__ __forceinline__ float ftanh(float x){
    float e = __expf(-2.0f * fabsf(x));
    float t = (1.0f - e) / (1.0f + e);
    return copysignf(t, x);
}
__device__ __forceinline__ ull ald(const ull* p){
    return __hip_atomic_load(p, __ATOMIC_RELAXED, __HIP_MEMORY_SCOPE_AGENT);
}
__device__ __forceinline__ void ast(unsigned int* p, unsigned int v){
    __hip_atomic_store(p, v, __ATOMIC_RELAXED, __HIP_MEMORY_SCOPE_AGENT);
}
__device__ __forceinline__ int min4(ull a, ull b){
    int x0 = (int)(unsigned)a, x1 = (int)(a >> 32);
    int x2 = (int)(unsigned)b, x3 = (int)(b >> 32);
    return min(min(x0, x1), min(x2, x3));
}

// ---------------------------------------------------------------------------
// prep: bf16 cast + bit-packed mask + zero flags
// ---------------------------------------------------------------------------
__global__ void prep_kernel(const float* __restrict__ x, unsigned int* __restrict__ xb,
                            unsigned int* __restrict__ mb, int* __restrict__ flags){
    const int s = blockIdx.x;     // sequence 0..63
    const int c = blockIdx.y;     // chunk 0..15 (64 timesteps each)
    const int l = threadIdx.x;    // 0..63
    if (s == 0 && c == 0 && l < 64) flags[l] = 0;   // replay-safe re-zero
    const float* xs = x + ((size_t)s * 1024 + (size_t)c * 64) * 128;
    unsigned int w0 = 0, w1 = 0;
    for (int tt = 0; tt < 64; ++tt){
        const float2 v = *(const float2*)(xs + (size_t)tt * 128 + 2 * l);
        bool nz = (v.x != 0.0f) || (v.y != 0.0f);
        unsigned long long b = __ballot(nz);
        if (b){ if (tt < 32) w0 |= 1u << tt; else w1 |= 1u << (tt - 32); }
        unsigned int p = (unsigned)f2bf(v.x) | ((unsigned)f2bf(v.y) << 16);
        xb[((size_t)s * 1024 + c * 64 + tt) * 64 + l] = p;
    }
    if (l == 0){ mb[s * 32 + c * 2] = w0; mb[s * 32 + c * 2 + 1] = w1; }
}

// ---------------------------------------------------------------------------
// one LSTM layer, pipelined against the previous layer via flags
// ---------------------------------------------------------------------------
template<int LAYER>
__device__ __forceinline__ void scan_layer(
    const unsigned int* xin,                  // L0: xb[seq][1024][64u32]; else hseq_prev [seq][1024][128u32]
    unsigned int* hout,                       // [seq][RM][128u32]
    const float* __restrict__ W, const float* __restrict__ U, const float* __restrict__ Bv,
    const unsigned int* __restrict__ mb,      // [64][32] mask bits
    float* __restrict__ hfinal,               // layer2 only
    int* flags)                               // [3][4][4]
{
    constexpr int DK = (LAYER == 0) ? 4 : 8;  // K-tiles of x part
    constexpr int KT = DK + 8;
    constexpr int RM = (LAYER == 2) ? 8 : 1024;   // ring size of hout
    const int bid = blockIdx.x & 15;
    const int g = bid >> 2, n = bid & 3;
    const int tid  = threadIdx.x;
    const int w    = tid >> 6;
    const int lane = tid & 63;
    const int l15  = lane & 15, lk = lane >> 4;
    const int up   = lane & 7,  s2 = lane >> 3;

    __shared__ float zw[4][16][68];
    __shared__ unsigned int mbL[16][32];
    __shared__ int sgl;
    if (tid == 0) sgl = 0;
    for (int i = tid; i < 512; i += 256)
        mbL[i >> 5][i & 31] = mb[(g * 16 + (i >> 5)) * 32 + (i & 31)];
    __syncthreads();
    if (tid < 16){
        int last = 0;
        #pragma unroll
        for (int q = 0; q < 32; ++q){
            unsigned v = mbL[tid][q];
            if (v) last = q * 32 + (32 - __clz(v));
        }
        atomicMax(&sgl, last);
    }

    // gate columns, bias, register-resident B fragments
    float bfr[4]; int gcol[4];
    #pragma unroll
    for (int nt = 0; nt < 4; ++nt){
        int lc = w * 64 + nt * 16 + l15;
        gcol[nt] = (lc & 3) * 256 + n * 64 + (lc >> 2);
        bfr[nt] = Bv[gcol[nt]];
    }
    bf16x8 Bf[KT][4];
    #pragma unroll
    for (int kt = 0; kt < KT; ++kt){
        const float* src = (kt < DK) ? (W + (size_t)(kt * 32 + lk * 8) * 1024)
                                     : (U + (size_t)((kt - DK) * 32 + lk * 8) * 1024);
        #pragma unroll
        for (int nt = 0; nt < 4; ++nt){
            bf16x8 v;
            #pragma unroll
            for (int j = 0; j < 8; ++j) v[j] = (short)f2bf(src[(size_t)j * 1024 + gcol[nt]]);
            Bf[kt][nt] = v;
        }
    }
    __syncthreads();
    const int gl = sgl;
    const ull* po = (const ull*)(flags + LAYER * 16 + g * 4);
    const ull* pp = (const ull*)(flags + (LAYER - 1) * 16 + g * 4);   // used only if LAYER>0

    float c00 = 0, c01 = 0, c10 = 0, c11 = 0;
    float h00 = 0, h01 = 0, h10 = 0, h11 = 0;
    const int myseq0 = g * 16 + s2, myseq1 = g * 16 + s2 + 8;
    const int hcol = n * 32 + w * 8 + up;

    for (int t = 0; t < gl; ++t){
        bf16x8 xa[DK];
        // L0 x loads: static data, issue before the poll (hide under spin)
        if (LAYER == 0){
            const unsigned int* xr = xin + ((size_t)(g * 16 + l15) * 1024 + t) * 64;
            #pragma unroll
            for (int kt = 0; kt < DK; ++kt) xa[kt] = *(const bf16x8*)(xr + kt * 16 + lk * 4);
        }
        // poll: prev layer published x(t)? siblings published h(t-1)?
        if (LAYER > 0 || t > 0){
            for (;;){
                bool ok = true;
                if (LAYER > 0) ok = (min4(ald(pp), ald(pp + 1)) >= t + 1);
                if (t > 0 && ok) ok = (min4(ald(po), ald(po + 1)) >= t);
                if (ok) break;
                __builtin_amdgcn_s_sleep(1);
            }
        }
        // coherent x loads (layers 1,2)
        if (LAYER > 0){
            const ull* xr = (const ull*)(xin + ((size_t)(g * 16 + l15) * 1024 + t) * 128);
            #pragma unroll
            for (int kt = 0; kt < DK; ++kt){
                union { ull q[2]; bf16x8 v; } u;
                u.q[0] = ald(xr + kt * 8 + lk * 2);
                u.q[1] = ald(xr + kt * 8 + lk * 2 + 1);
                xa[kt] = u.v;
            }
        }
        // coherent h(t-1) fragment loads
        bf16x8 ha[8];
        if (t > 0){
            const ull* hr = (const ull*)(hout + ((size_t)(g * 16 + l15) * RM + ((t - 1) & (RM - 1))) * 128);
            #pragma unroll
            for (int kh = 0; kh < 8; ++kh){
                union { ull q[2]; bf16x8 v; } u;
                u.q[0] = ald(hr + kh * 8 + lk * 2);
                u.q[1] = ald(hr + kh * 8 + lk * 2 + 1);
                ha[kh] = u.v;
            }
        }
        // MFMA: z = bias + x@W + h@U
        f32x4 acc[4];
        #pragma unroll
        for (int nt = 0; nt < 4; ++nt) acc[nt] = (f32x4){bfr[nt], bfr[nt], bfr[nt], bfr[nt]};
        #pragma unroll
        for (int kt = 0; kt < DK; ++kt)
            #pragma unroll
            for (int nt = 0; nt < 4; ++nt)
                acc[nt] = __builtin_amdgcn_mfma_f32_16x16x32_bf16(xa[kt], Bf[kt][nt], acc[nt], 0, 0, 0);
        if (t > 0){
            #pragma unroll
            for (int kh = 0; kh < 8; ++kh)
                #pragma unroll
                for (int nt = 0; nt < 4; ++nt)
                    acc[nt] = __builtin_amdgcn_mfma_f32_16x16x32_bf16(ha[kh], Bf[DK + kh][nt], acc[nt], 0, 0, 0);
        }
        // transpose z via wave-private LDS, then gates
        #pragma unroll
        for (int nt = 0; nt < 4; ++nt)
            #pragma unroll
            for (int r = 0; r < 4; ++r)
                zw[w][lk * 4 + r][nt * 16 + l15] = acc[nt][r];
        asm volatile("s_waitcnt lgkmcnt(0)" ::: "memory");
        __builtin_amdgcn_sched_barrier(0);

        bool m0 = (mbL[s2][t >> 5]     >> (t & 31)) & 1;
        bool m1 = (mbL[s2 + 8][t >> 5] >> (t & 31)) & 1;
        const float* z0 = &zw[w][s2][up * 8];
        const float* z1 = &zw[w][s2 + 8][up * 8];
        float cn, hn;
        cn = fsig(z0[1]) * c00 + fsig(z0[0]) * ftanh(z0[2]); hn = fsig(z0[3]) * ftanh(cn);
        if (m0){ c00 = cn; h00 = hn; }
        cn = fsig(z0[5]) * c01 + fsig(z0[4]) * ftanh(z0[6]); hn = fsig(z0[7]) * ftanh(cn);
        if (m0){ c01 = cn; h01 = hn; }
        cn = fsig(z1[1]) * c10 + fsig(z1[0]) * ftanh(z1[2]); hn = fsig(z1[3]) * ftanh(cn);
        if (m1){ c10 = cn; h10 = hn; }
        cn = fsig(z1[5]) * c11 + fsig(z1[4]) * ftanh(z1[6]); hn = fsig(z1[7]) * ftanh(cn);
        if (m1){ c11 = cn; h11 = hn; }

        // publish h(t) (write-through sc1), then flag after block-wide drain
        unsigned p0 = (unsigned)f2bf(h00) | ((unsigned)f2bf(h01) << 16);
        unsigned p1 = (unsigned)f2bf(h10) | ((unsigned)f2bf(h11) << 16);
        int trow = t & (RM - 1);
        ast(hout + ((size_t)myseq0 * RM + trow) * 128 + hcol, p0);
        ast(hout + ((size_t)myseq1 * RM + trow) * 128 + hcol, p1);
        __syncthreads();   // emits vmcnt(0) drain before barrier -> stores visible
        if (tid == 0)
            __hip_atomic_store(flags + LAYER * 16 + g * 4 + n, t + 1,
                               __ATOMIC_RELEASE, __HIP_MEMORY_SCOPE_AGENT);
    }

    if (LAYER == 2){
        const int colb = n * 64 + w * 16 + up * 2;
        hfinal[(size_t)myseq0 * 256 + colb]     = h00;
        hfinal[(size_t)myseq0 * 256 + colb + 1] = h01;
        hfinal[(size_t)myseq1 * 256 + colb]     = h10;
        hfinal[(size_t)myseq1 * 256 + colb + 1] = h11;
    }
}

__global__ __launch_bounds__(256, 1) void scan3_kernel(
    const unsigned int* xb, unsigned int* h0, unsigned int* h1, unsigned int* h2,
    const float* W0, const float* U0, const float* b0,
    const float* W1, const float* U1, const float* b1,
    const float* W2, const float* U2, const float* b2,
    const unsigned int* mb, int* flags, float* hfinal)
{
    const int layer = blockIdx.x >> 4;
    if (layer == 0)      scan_layer<0>(xb, h0, W0, U0, b0, mb, nullptr, flags);
    else if (layer == 1) scan_layer<1>(h0, h1, W1, U1, b1, mb, nullptr, flags);
    else                 scan_layer<2>(h1, h2, W2, U2, b2, mb, hfinal,  flags);
}

// ---------------------------------------------------------------------------
__global__ void final_kernel(const float* __restrict__ hfinal, const float* __restrict__ dw,
                             const float* __restrict__ db, float* __restrict__ out){
    const int b = threadIdx.x >> 3, j = threadIdx.x & 7;
    const float* ha = hfinal + (size_t)(2 * b) * 256;
    const float* hb = ha + 256;
    float s = 0.0f;
    for (int d = j; d < 256; d += 8){ float df = ha[d] - hb[d]; s += df * df; }
    #pragma unroll
    for (int off = 4; off; off >>= 1) s += __shfl_xor(s, off, 8);
    if (j == 0){
        float dist = sqrtf(s);
        dist = fminf(fmaxf(dist, 1e-7f), 1e7f);
        out[b] = fsig(dist * dw[0] + db[0]);
    }
}

// ---------------------------------------------------------------------------
extern "C" void kernel_launch(void* const* d_in, const int* in_sizes, int n_in,
                              void* d_out, int out_size, void* d_ws, size_t ws_size,
                              hipStream_t stream){
    const float* x  = (const float*)d_in[0];
    const float* W0 = (const float*)d_in[1];
    const float* U0 = (const float*)d_in[2];
    const float* b0 = (const float*)d_in[3];
    const float* W1 = (const float*)d_in[4];
    const float* U1 = (const float*)d_in[5];
    const float* b1 = (const float*)d_in[6];
    const float* W2 = (const float*)d_in[7];
    const float* U2 = (const float*)d_in[8];
    const float* b2 = (const float*)d_in[9];
    const float* dw = (const float*)d_in[10];
    const float* db = (const float*)d_in[11];

    // workspace layout (~80.3 MB)
    char* ws = (char*)d_ws;
    unsigned int* xb     = (unsigned int*)(ws);                    // 16 MB
    unsigned int* h0     = (unsigned int*)(ws + 16777216ull);      // 32 MB
    unsigned int* h1     = (unsigned int*)(ws + 50331648ull);      // 32 MB
    unsigned int* h2     = (unsigned int*)(ws + 83886080ull);      // 256 KB ring
    unsigned int* mb     = (unsigned int*)(ws + 84148224ull);      // 8 KB
    int*          flags  = (int*)(ws + 84156416ull);               // 256 B
    float*        hfinal = (float*)(ws + 84156672ull);             // 64 KB
    float*        out    = (float*)d_out;

    prep_kernel<<<dim3(64, 16), 64, 0, stream>>>(x, xb, mb, flags);
    scan3_kernel<<<48, 256, 0, stream>>>(xb, h0, h1, h2,
                                         W0, U0, b0, W1, U1, b1, W2, U2, b2,
                                         mb, flags, hfinal);
    final_kernel<<<1, 256, 0, stream>>>(hfinal, dw, db, out);
}

// Round 4
// 6079.048 us; speedup vs baseline: 2.4616x; 1.1453x over previous
//
#include <hip/hip_runtime.h>

// ============================================================================
// Siamese 3-layer masked LSTM (B=32, 2 sides, T=1024, F=128, H=256)
// Fused pipelined design (round-2 structure, fence-free sync):
//   prep:  bit-mask mb[64][32], x -> bf16 xb, zero flags
//   scan3: ONE launch, 48 blocks = 3 layers x 4 groups x 4 N-slices.
//          Layer l step t consumes layer l-1 step t (1-step lag) and its own
//          siblings' h(t-1). ALL cross-block traffic is RELAXED agent-scope
//          (sc1) loads/stores -- no RELEASE/ACQUIRE anywhere in the loop, so
//          no buffer_wbl2 / buffer_inv cache walks (round-2's 6.9us/step bug).
//          Ordering: data stores drained by explicit s_waitcnt vmcnt(0) +
//          __syncthreads(), THEN the relaxed flag store (t+1). Observers that
//          see the flag therefore see the data (both at the IF coherence pt).
//          Weights live in ~256 registers/thread as MFMA B-fragments.
//   final: dist = ||h1-h2||, sigmoid(dist*w+b)
// ============================================================================

typedef __attribute__((ext_vector_type(8))) short bf16x8;
typedef __attribute__((ext_vector_type(4))) float f32x4;
typedef unsigned long long ull;

__device__ __forceinline__ unsigned short f2bf(float f){
    unsigned u = __float_as_uint(f);
    u += 0x7FFFu + ((u >> 16) & 1u);        // round-to-nearest-even
    return (unsigned short)(u >> 16);
}
__device__ __forceinline__ float fsig(float x){ return 1.0f / (1.0f + __expf(-x)); }
__device__ __forceinline__ float ftanh(float x){
    float e = __expf(-2.0f * fabsf(x));
    float t = (1.0f - e) / (1.0f + e);
    return copysignf(t, x);
}
__device__ __forceinline__ ull ald(const ull* p){
    return __hip_atomic_load(p, __ATOMIC_RELAXED, __HIP_MEMORY_SCOPE_AGENT);
}
__device__ __forceinline__ void ast(unsigned int* p, unsigned int v){
    __hip_atomic_store(p, v, __ATOMIC_RELAXED, __HIP_MEMORY_SCOPE_AGENT);
}
__device__ __forceinline__ int min4(ull a, ull b){
    int x0 = (int)(unsigned)a, x1 = (int)(a >> 32);
    int x2 = (int)(unsigned)b, x3 = (int)(b >> 32);
    return min(min(x0, x1), min(x2, x3));
}

// ---------------------------------------------------------------------------
// prep: bf16 cast + bit-packed mask + zero flags
// ---------------------------------------------------------------------------
__global__ void prep_kernel(const float* __restrict__ x, unsigned int* __restrict__ xb,
                            unsigned int* __restrict__ mb, int* __restrict__ fl){
    const int s = blockIdx.x, c = blockIdx.y, l = threadIdx.x;
    if (s == 0 && c == 0){ for (int i = l; i < 256; i += 64) fl[i] = 0; }  // replay-safe
    const float* xs = x + ((size_t)s * 1024 + (size_t)c * 64) * 128;
    unsigned int w0 = 0, w1 = 0;
    for (int tt = 0; tt < 64; ++tt){
        const float2 v = *(const float2*)(xs + (size_t)tt * 128 + 2 * l);
        bool nz = (v.x != 0.0f) || (v.y != 0.0f);
        unsigned long long b = __ballot(nz);
        if (b){ if (tt < 32) w0 |= 1u << tt; else w1 |= 1u << (tt - 32); }
        unsigned int p = (unsigned)f2bf(v.x) | ((unsigned)f2bf(v.y) << 16);
        xb[((size_t)s * 1024 + c * 64 + tt) * 64 + l] = p;
    }
    if (l == 0){ mb[s * 32 + c * 2] = w0; mb[s * 32 + c * 2 + 1] = w1; }
}

// ---------------------------------------------------------------------------
// one LSTM layer, pipelined against the previous layer via flags
// ---------------------------------------------------------------------------
template<int LAYER>
__device__ __forceinline__ void scan_layer(
    const unsigned int* xin,                  // L0: xb[seq][1024][64]; else hseq_prev [seq][1024][128]
    unsigned int* hout,                       // [seq][RM][128] (L0/L1: RM=1024; L2: RM=8 ring)
    const float* __restrict__ W, const float* __restrict__ U, const float* __restrict__ Bv,
    const unsigned int* __restrict__ mb,      // [64][32] mask bits
    float* __restrict__ hfinal,               // layer2 only
    int* flags)                               // [3][4][16]: +0..3 sibling, +4..7 inter-layer
{
    constexpr int DK = (LAYER == 0) ? 4 : 8;
    constexpr int KT = DK + 8;
    constexpr int RM = (LAYER == 2) ? 8 : 1024;
    const int bid = blockIdx.x & 15;
    const int g = bid >> 2, n = bid & 3;
    const int tid  = threadIdx.x;
    const int w    = tid >> 6;
    const int lane = tid & 63;
    const int l15  = lane & 15, lk = lane >> 4;
    const int up   = lane & 7,  s2 = lane >> 3;

    __shared__ float zw[4][16][68];
    __shared__ unsigned int mbL[16][32];
    __shared__ int sgl;
    if (tid == 0) sgl = 0;
    for (int i = tid; i < 512; i += 256)
        mbL[i >> 5][i & 31] = mb[(g * 16 + (i >> 5)) * 32 + (i & 31)];
    __syncthreads();
    if (tid < 16){
        int last = 0;
        #pragma unroll
        for (int q = 0; q < 32; ++q){
            unsigned v = mbL[tid][q];
            if (v) last = q * 32 + (32 - __clz(v));
        }
        atomicMax(&sgl, last);
    }

    // gate columns, bias, register-resident B fragments
    float bfr[4]; int gcol[4];
    #pragma unroll
    for (int nt = 0; nt < 4; ++nt){
        int lc = w * 64 + nt * 16 + l15;
        gcol[nt] = (lc & 3) * 256 + n * 64 + (lc >> 2);
        bfr[nt] = Bv[gcol[nt]];
    }
    bf16x8 Bf[KT][4];
    #pragma unroll
    for (int kt = 0; kt < KT; ++kt){
        const float* src = (kt < DK) ? (W + (size_t)(kt * 32 + lk * 8) * 1024)
                                     : (U + (size_t)((kt - DK) * 32 + lk * 8) * 1024);
        #pragma unroll
        for (int nt = 0; nt < 4; ++nt){
            bf16x8 v;
            #pragma unroll
            for (int j = 0; j < 8; ++j) v[j] = (short)f2bf(src[(size_t)j * 1024 + gcol[nt]]);
            Bf[kt][nt] = v;
        }
    }
    __syncthreads();
    const int gl = sgl;
    int* pF  = flags + (LAYER * 4 + g) * 16;                       // sibling flags (4)
    int* pFg = flags + (LAYER * 4 + g) * 16 + 4;                   // my inter-layer flags
    int* pG  = flags + ((LAYER > 0 ? LAYER - 1 : 0) * 4 + g) * 16 + 4;  // prev layer's

    float c00 = 0, c01 = 0, c10 = 0, c11 = 0;
    float h00 = 0, h01 = 0, h10 = 0, h11 = 0;
    const int myseq0 = g * 16 + s2, myseq1 = g * 16 + s2 + 8;
    const int hcol = n * 32 + w * 8 + up;

    for (int t = 0; t < gl; ++t){
        // ---- L0 x loads: issued (relaxed atomics, can't sink) before poll ---
        bf16x8 xa[DK];
        if (LAYER == 0){
            const ull* xr = (const ull*)(xin + ((size_t)(g * 16 + l15) * 1024 + t) * 64) + lk * 2;
            #pragma unroll
            for (int kt = 0; kt < DK; ++kt){
                union { ull q[2]; bf16x8 v; } u;
                u.q[0] = ald(xr + kt * 8);
                u.q[1] = ald(xr + kt * 8 + 1);
                xa[kt] = u.v;
            }
        }
        // ---- poll: prev layer published h_prev(t)? siblings published h(t-1)?
        if (LAYER > 0 || t > 0){
            const ull* f  = (const ull*)pF;
            const ull* gq = (const ull*)pG;
            for (;;){
                bool ok = true;
                if (t > 0)              ok = (min4(ald(f),  ald(f + 1))  >= t);
                if (LAYER > 0 && ok)    ok = (min4(ald(gq), ald(gq + 1)) >= t + 1);
                if (ok) break;
            }
        }
        // ---- x loads (layers 1,2) first, then h loads: compiler's counted
        //      vmcnt lets x-MFMA run while h fragments are still in flight ----
        if (LAYER > 0){
            const ull* xr = (const ull*)(xin + ((size_t)(g * 16 + l15) * 1024 + t) * 128) + lk * 2;
            #pragma unroll
            for (int kt = 0; kt < DK; ++kt){
                union { ull q[2]; bf16x8 v; } u;
                u.q[0] = ald(xr + kt * 8);
                u.q[1] = ald(xr + kt * 8 + 1);
                xa[kt] = u.v;
            }
        }
        bf16x8 ha[8];
        if (t > 0){
            const ull* hr = (const ull*)(hout + ((size_t)(g * 16 + l15) * RM + ((t - 1) & (RM - 1))) * 128) + lk * 2;
            #pragma unroll
            for (int kh = 0; kh < 8; ++kh){
                union { ull q[2]; bf16x8 v; } u;
                u.q[0] = ald(hr + kh * 8);
                u.q[1] = ald(hr + kh * 8 + 1);
                ha[kh] = u.v;
            }
        }
        // ---- MFMA: z = bias + x@W + h@U --------------------------------------
        f32x4 acc[4];
        #pragma unroll
        for (int nt = 0; nt < 4; ++nt) acc[nt] = (f32x4){bfr[nt], bfr[nt], bfr[nt], bfr[nt]};
        #pragma unroll
        for (int kt = 0; kt < DK; ++kt)
            #pragma unroll
            for (int nt = 0; nt < 4; ++nt)
                acc[nt] = __builtin_amdgcn_mfma_f32_16x16x32_bf16(xa[kt], Bf[kt][nt], acc[nt], 0, 0, 0);
        if (t > 0){
            #pragma unroll
            for (int kh = 0; kh < 8; ++kh)
                #pragma unroll
                for (int nt = 0; nt < 4; ++nt)
                    acc[nt] = __builtin_amdgcn_mfma_f32_16x16x32_bf16(ha[kh], Bf[DK + kh][nt], acc[nt], 0, 0, 0);
        }
        // ---- transpose z via wave-private LDS, then gates --------------------
        #pragma unroll
        for (int nt = 0; nt < 4; ++nt)
            #pragma unroll
            for (int r = 0; r < 4; ++r)
                zw[w][lk * 4 + r][nt * 16 + l15] = acc[nt][r];
        asm volatile("s_waitcnt lgkmcnt(0)" ::: "memory");
        __builtin_amdgcn_sched_barrier(0);

        bool m0 = (mbL[s2][t >> 5]     >> (t & 31)) & 1;
        bool m1 = (mbL[s2 + 8][t >> 5] >> (t & 31)) & 1;
        const float* z0 = &zw[w][s2][up * 8];
        const float* z1 = &zw[w][s2 + 8][up * 8];
        float cn, hn;
        cn = fsig(z0[1]) * c00 + fsig(z0[0]) * ftanh(z0[2]); hn = fsig(z0[3]) * ftanh(cn);
        if (m0){ c00 = cn; h00 = hn; }
        cn = fsig(z0[5]) * c01 + fsig(z0[4]) * ftanh(z0[6]); hn = fsig(z0[7]) * ftanh(cn);
        if (m0){ c01 = cn; h01 = hn; }
        cn = fsig(z1[1]) * c10 + fsig(z1[0]) * ftanh(z1[2]); hn = fsig(z1[3]) * ftanh(cn);
        if (m1){ c10 = cn; h10 = hn; }
        cn = fsig(z1[5]) * c11 + fsig(z1[4]) * ftanh(z1[6]); hn = fsig(z1[7]) * ftanh(cn);
        if (m1){ c11 = cn; h11 = hn; }

        // ---- publish h(t): relaxed sc1 stores, drain, barrier, relaxed flag --
        unsigned p0 = (unsigned)f2bf(h00) | ((unsigned)f2bf(h01) << 16);
        unsigned p1 = (unsigned)f2bf(h10) | ((unsigned)f2bf(h11) << 16);
        int trow = t & (RM - 1);
        ast(hout + ((size_t)myseq0 * RM + trow) * 128 + hcol, p0);
        ast(hout + ((size_t)myseq1 * RM + trow) * 128 + hcol, p1);
        asm volatile("s_waitcnt vmcnt(0)" ::: "memory");   // data acked at coherence pt
        __syncthreads();                                   // all waves drained
        if (tid == 0){
            ast((unsigned*)(pF + n), (unsigned)(t + 1));               // sibling: h(t) ready
            if (LAYER < 2) ast((unsigned*)(pFg + n), (unsigned)(t + 1)); // next layer: h(t) ready
        }
    }

    if (LAYER == 2){
        const int colb = n * 64 + w * 16 + up * 2;
        hfinal[(size_t)myseq0 * 256 + colb]     = h00;
        hfinal[(size_t)myseq0 * 256 + colb + 1] = h01;
        hfinal[(size_t)myseq1 * 256 + colb]     = h10;
        hfinal[(size_t)myseq1 * 256 + colb + 1] = h11;
    }
}

__global__ __launch_bounds__(256, 1) void scan3_kernel(
    const unsigned int* xb, unsigned int* h0, unsigned int* h1, unsigned int* h2,
    const float* W0, const float* U0, const float* b0,
    const float* W1, const float* U1, const float* b1,
    const float* W2, const float* U2, const float* b2,
    const unsigned int* mb, int* flags, float* hfinal)
{
    const int layer = blockIdx.x >> 4;
    if (layer == 0)      scan_layer<0>(xb, h0, W0, U0, b0, mb, nullptr, flags);
    else if (layer == 1) scan_layer<1>(h0, h1, W1, U1, b1, mb, nullptr, flags);
    else                 scan_layer<2>(h1, h2, W2, U2, b2, mb, hfinal,  flags);
}

// ---------------------------------------------------------------------------
__global__ void final_kernel(const float* __restrict__ hfinal, const float* __restrict__ dw,
                             const float* __restrict__ db, float* __restrict__ out){
    const int b = threadIdx.x >> 3, j = threadIdx.x & 7;
    const float* ha = hfinal + (size_t)(2 * b) * 256;
    const float* hb = ha + 256;
    float s = 0.0f;
    for (int d = j; d < 256; d += 8){ float df = ha[d] - hb[d]; s += df * df; }
    #pragma unroll
    for (int off = 4; off; off >>= 1) s += __shfl_xor(s, off, 8);
    if (j == 0){
        float dist = sqrtf(s);
        dist = fminf(fmaxf(dist, 1e-7f), 1e7f);
        out[b] = fsig(dist * dw[0] + db[0]);
    }
}

// ---------------------------------------------------------------------------
extern "C" void kernel_launch(void* const* d_in, const int* in_sizes, int n_in,
                              void* d_out, int out_size, void* d_ws, size_t ws_size,
                              hipStream_t stream){
    const float* x  = (const float*)d_in[0];
    const float* W0 = (const float*)d_in[1];
    const float* U0 = (const float*)d_in[2];
    const float* b0 = (const float*)d_in[3];
    const float* W1 = (const float*)d_in[4];
    const float* U1 = (const float*)d_in[5];
    const float* b1 = (const float*)d_in[6];
    const float* W2 = (const float*)d_in[7];
    const float* U2 = (const float*)d_in[8];
    const float* b2 = (const float*)d_in[9];
    const float* dw = (const float*)d_in[10];
    const float* db = (const float*)d_in[11];

    char* ws = (char*)d_ws;
    unsigned int* xb     = (unsigned int*)(ws);                    // 16 MB
    unsigned int* h0     = (unsigned int*)(ws + 16777216ull);      // 32 MB
    unsigned int* h1     = (unsigned int*)(ws + 50331648ull);      // 32 MB
    unsigned int* h2     = (unsigned int*)(ws + 83886080ull);      // 256 KB ring
    unsigned int* mb     = (unsigned int*)(ws + 84148224ull);      // 8 KB
    int*          flags  = (int*)(ws + 84156416ull);               // 256 ints
    float*        hfinal = (float*)(ws + 84157440ull);             // 64 KB
    float*        out    = (float*)d_out;

    prep_kernel<<<dim3(64, 16), 64, 0, stream>>>(x, xb, mb, flags);
    scan3_kernel<<<48, 256, 0, stream>>>(xb, h0, h1, h2,
                                         W0, U0, b0, W1, U1, b1, W2, U2, b2,
                                         mb, flags, hfinal);
    final_kernel<<<1, 256, 0, stream>>>(hfinal, dw, db, out);
}

// Round 5
// 3307.965 us; speedup vs baseline: 4.5237x; 1.8377x over previous
//
#include <hip/hip_runtime.h>

// ============================================================================
// Siamese 3-layer masked LSTM (B=32, 2 sides, T=1024, F=128, H=256)
// Fused pipelined design, COALESCED fragment-major exchange:
//   All cross-block tensors (xb, hseq0, hseq1, hx2) are stored in MFMA
//   A-fragment-major layout per (t, group):
//     word[(kt*4+lk)*64 + seq*4 + j2]  <=>  lane (lk*16+seq) 16B chunk kt
//   so consumers load h(t-1) and x(t) with 8x global_load_dwordx4 sc1 that
//   are perfectly coalesced (1KB contiguous per wave instruction), replacing
//   round-4's scattered per-lane 8B atomic loads (~16x fewer IF transactions,
//   which round-4 counters showed to be the bottleneck).
//   Sync protocol (round-4 proven): relaxed sc1 data stores -> s_waitcnt
//   vmcnt(0) -> __syncthreads -> relaxed flag store; pollers use relaxed
//   agent atomic loads. No RELEASE/ACQUIRE anywhere in the loop.
//   Weights live in ~256 registers/thread as MFMA B-fragments.
// ============================================================================

typedef __attribute__((ext_vector_type(8))) short bf16x8;
typedef __attribute__((ext_vector_type(4))) float f32x4;
typedef __attribute__((ext_vector_type(4))) unsigned int u32x4;
typedef unsigned long long ull;

__device__ __forceinline__ unsigned short f2bf(float f){
    unsigned u = __float_as_uint(f);
    u += 0x7FFFu + ((u >> 16) & 1u);        // round-to-nearest-even
    return (unsigned short)(u >> 16);
}
__device__ __forceinline__ float fsig(float x){ return 1.0f / (1.0f + __expf(-x)); }
__device__ __forceinline__ float ftanh(float x){
    float e = __expf(-2.0f * fabsf(x));
    float t = (1.0f - e) / (1.0f + e);
    return copysignf(t, x);
}
__device__ __forceinline__ ull ald(const ull* p){
    return __hip_atomic_load(p, __ATOMIC_RELAXED, __HIP_MEMORY_SCOPE_AGENT);
}
__device__ __forceinline__ void ast(unsigned int* p, unsigned int v){
    __hip_atomic_store(p, v, __ATOMIC_RELAXED, __HIP_MEMORY_SCOPE_AGENT);
}
__device__ __forceinline__ int min4(ull a, ull b){
    int x0 = (int)(unsigned)a, x1 = (int)(a >> 32);
    int x2 = (int)(unsigned)b, x3 = (int)(b >> 32);
    return min(min(x0, x1), min(x2, x3));
}

// coalesced 4x dwordx4 from base P (per-lane), offsets 0,1K,2K,3K
#define LOAD4_SC1(P, O0,O1,O2,O3)                                        \
  asm volatile("global_load_dwordx4 %0, %4, off sc1\n\t"                 \
               "global_load_dwordx4 %1, %4, off offset:1024 sc1\n\t"     \
               "global_load_dwordx4 %2, %4, off offset:2048 sc1\n\t"     \
               "global_load_dwordx4 %3, %4, off offset:3072 sc1"         \
               : "=&v"(O0),"=&v"(O1),"=&v"(O2),"=&v"(O3)                 \
               : "v"(P) : "memory")
#define LOAD4_PLAIN(P, O0,O1,O2,O3)                                      \
  asm volatile("global_load_dwordx4 %0, %4, off\n\t"                     \
               "global_load_dwordx4 %1, %4, off offset:1024\n\t"         \
               "global_load_dwordx4 %2, %4, off offset:2048\n\t"         \
               "global_load_dwordx4 %3, %4, off offset:3072"             \
               : "=&v"(O0),"=&v"(O1),"=&v"(O2),"=&v"(O3)                 \
               : "v"(P) : "memory")

// ---------------------------------------------------------------------------
// prep: bf16 cast into fragment-major xb + bit-packed mask + zero flags
// ---------------------------------------------------------------------------
__global__ void prep_kernel(const float* __restrict__ x, unsigned int* __restrict__ xb,
                            unsigned int* __restrict__ mb, int* __restrict__ fl){
    const int s = blockIdx.x, c = blockIdx.y, l = threadIdx.x;
    if (s == 0 && c == 0){ for (int i = l; i < 256; i += 64) fl[i] = 0; }  // replay-safe
    const int g = s >> 4, sg = s & 15;
    // feature pair (2l,2l+1): word offset within 4KB group-block
    const int woff = ((l >> 4) * 4 + ((l >> 2) & 3)) * 64 + sg * 4 + (l & 3);
    const float* xs = x + ((size_t)s * 1024 + (size_t)c * 64) * 128;
    unsigned int w0 = 0, w1 = 0;
    for (int tt = 0; tt < 64; ++tt){
        const float2 v = *(const float2*)(xs + (size_t)tt * 128 + 2 * l);
        bool nz = (v.x != 0.0f) || (v.y != 0.0f);
        unsigned long long b = __ballot(nz);
        if (b){ if (tt < 32) w0 |= 1u << tt; else w1 |= 1u << (tt - 32); }
        unsigned int p = (unsigned)f2bf(v.x) | ((unsigned)f2bf(v.y) << 16);
        xb[((size_t)(c * 64 + tt) * 4 + g) * 1024 + woff] = p;
    }
    if (l == 0){ mb[s * 32 + c * 2] = w0; mb[s * 32 + c * 2 + 1] = w1; }
}

// ---------------------------------------------------------------------------
// one LSTM layer, pipelined against the previous layer via flags
// ---------------------------------------------------------------------------
template<int LAYER>
__device__ __forceinline__ void scan_layer(
    const unsigned int* xin,                  // fragment-major: L0 1024 w/blk, else 2048 w/blk
    unsigned int* hout,                       // fragment-major: 2048 w/blk; L2: 8-slot ring
    const float* __restrict__ W, const float* __restrict__ U, const float* __restrict__ Bv,
    const unsigned int* __restrict__ mb,      // [64][32] mask bits
    float* __restrict__ hfinal,               // layer2 only
    int* flags)                               // [12][16]: +0..3 sibling/inter-layer
{
    constexpr int DK = (LAYER == 0) ? 4 : 8;
    constexpr int KT = DK + 8;
    const int bid = blockIdx.x & 15;
    const int g = bid >> 2, n = bid & 3;
    const int tid  = threadIdx.x;
    const int w    = tid >> 6;
    const int lane = tid & 63;
    const int l15  = lane & 15, lk = lane >> 4;
    const int up   = lane & 7,  s2 = lane >> 3;

    __shared__ float zw[4][16][68];
    __shared__ unsigned int mbL[16][32];
    __shared__ int sgl;
    if (tid == 0) sgl = 0;
    for (int i = tid; i < 512; i += 256)
        mbL[i >> 5][i & 31] = mb[(g * 16 + (i >> 5)) * 32 + (i & 31)];
    __syncthreads();
    if (tid < 16){
        int last = 0;
        #pragma unroll
        for (int q = 0; q < 32; ++q){
            unsigned v = mbL[tid][q];
            if (v) last = q * 32 + (32 - __clz(v));
        }
        atomicMax(&sgl, last);
    }

    // gate columns, bias, register-resident B fragments
    float bfr[4]; int gcol[4];
    #pragma unroll
    for (int nt = 0; nt < 4; ++nt){
        int lc = w * 64 + nt * 16 + l15;
        gcol[nt] = (lc & 3) * 256 + n * 64 + (lc >> 2);
        bfr[nt] = Bv[gcol[nt]];
    }
    bf16x8 Bf[KT][4];
    #pragma unroll
    for (int kt = 0; kt < KT; ++kt){
        const float* src = (kt < DK) ? (W + (size_t)(kt * 32 + lk * 8) * 1024)
                                     : (U + (size_t)((kt - DK) * 32 + lk * 8) * 1024);
        #pragma unroll
        for (int nt = 0; nt < 4; ++nt){
            bf16x8 v;
            #pragma unroll
            for (int j = 0; j < 8; ++j) v[j] = (short)f2bf(src[(size_t)j * 1024 + gcol[nt]]);
            Bf[kt][nt] = v;
        }
    }
    __syncthreads();
    const int gl = sgl;
    int* pF  = flags + (LAYER * 4 + g) * 16;                            // sibling flags (4)
    int* pG  = flags + ((LAYER > 0 ? LAYER - 1 : 0) * 4 + g) * 16;      // prev-layer flags

    float c00 = 0, c01 = 0, c10 = 0, c11 = 0;
    float h00 = 0, h01 = 0, h10 = 0, h11 = 0;
    const int myseq0 = g * 16 + s2, myseq1 = g * 16 + s2 + 8;
    const int hcol = n * 32 + w * 8 + up;
    // producer word offset: hid pair (2*hcol, 2*hcol+1), row s2 (p0) / s2+8 (p1)
    const int woff0 = ((hcol >> 4) * 4 + ((hcol >> 2) & 3)) * 64 + s2 * 4 + (hcol & 3);

    for (int t = 0; t < gl; ++t){
        u32x4 x0v,x1v,x2v,x3v,x4v,x5v,x6v,x7v;
        u32x4 h0v,h1v,h2v,h3v,h4v,h5v,h6v,h7v;
        // ---- L0 x loads: plain coalesced, issued before poll -----------------
        if (LAYER == 0){
            ull xaddr = (ull)((const char*)(xin + ((size_t)t * 4 + g) * 1024) + lane * 16);
            LOAD4_PLAIN(xaddr, x0v, x1v, x2v, x3v);
        }
        // ---- poll: siblings h(t-1) ready? prev layer x(t) ready? -------------
        if (LAYER > 0 || t > 0){
            const ull* f  = (const ull*)pF;
            const ull* gq = (const ull*)pG;
            int spins = 0;
            for (;;){
                bool ok = true;
                if (t > 0)           ok = (min4(ald(f),  ald(f + 1))  >= t);
                if (LAYER > 0 && ok) ok = (min4(ald(gq), ald(gq + 1)) >= t + 1);
                if (ok) break;
                if ((++spins & 63) == 0) __builtin_amdgcn_s_sleep(1);
            }
        }
        // ---- coalesced fragment loads (sc1: coherence-point data) ------------
        if (LAYER > 0){
            ull xaddr = (ull)((const char*)(xin + ((size_t)t * 4 + g) * 2048) + lane * 16);
            LOAD4_SC1(xaddr,        x0v, x1v, x2v, x3v);
            LOAD4_SC1(xaddr + 4096, x4v, x5v, x6v, x7v);
        }
        if (t > 0){
            size_t hb = ((size_t)(LAYER == 2 ? ((t - 1) & 7) : (t - 1)) * 4 + g) * 2048;
            ull haddr = (ull)((const char*)(hout + hb) + lane * 16);
            LOAD4_SC1(haddr,        h0v, h1v, h2v, h3v);
            LOAD4_SC1(haddr + 4096, h4v, h5v, h6v, h7v);
        }
        asm volatile("s_waitcnt vmcnt(0)" ::: "memory");
        __builtin_amdgcn_sched_barrier(0);

        // ---- MFMA: z = bias + x@W + h@U --------------------------------------
        bf16x8 xa[DK];
        xa[0] = __builtin_bit_cast(bf16x8, x0v); xa[1] = __builtin_bit_cast(bf16x8, x1v);
        xa[2] = __builtin_bit_cast(bf16x8, x2v); xa[3] = __builtin_bit_cast(bf16x8, x3v);
        if (LAYER > 0){
            xa[DK - 4] = __builtin_bit_cast(bf16x8, x4v); xa[DK - 3] = __builtin_bit_cast(bf16x8, x5v);
            xa[DK - 2] = __builtin_bit_cast(bf16x8, x6v); xa[DK - 1] = __builtin_bit_cast(bf16x8, x7v);
        }
        f32x4 acc[4];
        #pragma unroll
        for (int nt = 0; nt < 4; ++nt) acc[nt] = (f32x4){bfr[nt], bfr[nt], bfr[nt], bfr[nt]};
        #pragma unroll
        for (int kt = 0; kt < DK; ++kt)
            #pragma unroll
            for (int nt = 0; nt < 4; ++nt)
                acc[nt] = __builtin_amdgcn_mfma_f32_16x16x32_bf16(xa[kt], Bf[kt][nt], acc[nt], 0, 0, 0);
        if (t > 0){
            bf16x8 ha[8];
            ha[0] = __builtin_bit_cast(bf16x8, h0v); ha[1] = __builtin_bit_cast(bf16x8, h1v);
            ha[2] = __builtin_bit_cast(bf16x8, h2v); ha[3] = __builtin_bit_cast(bf16x8, h3v);
            ha[4] = __builtin_bit_cast(bf16x8, h4v); ha[5] = __builtin_bit_cast(bf16x8, h5v);
            ha[6] = __builtin_bit_cast(bf16x8, h6v); ha[7] = __builtin_bit_cast(bf16x8, h7v);
            #pragma unroll
            for (int kh = 0; kh < 8; ++kh)
                #pragma unroll
                for (int nt = 0; nt < 4; ++nt)
                    acc[nt] = __builtin_amdgcn_mfma_f32_16x16x32_bf16(ha[kh], Bf[DK + kh][nt], acc[nt], 0, 0, 0);
        }
        // ---- transpose z via wave-private LDS, then gates --------------------
        #pragma unroll
        for (int nt = 0; nt < 4; ++nt)
            #pragma unroll
            for (int r = 0; r < 4; ++r)
                zw[w][lk * 4 + r][nt * 16 + l15] = acc[nt][r];
        asm volatile("s_waitcnt lgkmcnt(0)" ::: "memory");
        __builtin_amdgcn_sched_barrier(0);

        bool m0 = (mbL[s2][t >> 5]     >> (t & 31)) & 1;
        bool m1 = (mbL[s2 + 8][t >> 5] >> (t & 31)) & 1;
        const float* z0 = &zw[w][s2][up * 8];
        const float* z1 = &zw[w][s2 + 8][up * 8];
        float cn, hn;
        cn = fsig(z0[1]) * c00 + fsig(z0[0]) * ftanh(z0[2]); hn = fsig(z0[3]) * ftanh(cn);
        if (m0){ c00 = cn; h00 = hn; }
        cn = fsig(z0[5]) * c01 + fsig(z0[4]) * ftanh(z0[6]); hn = fsig(z0[7]) * ftanh(cn);
        if (m0){ c01 = cn; h01 = hn; }
        cn = fsig(z1[1]) * c10 + fsig(z1[0]) * ftanh(z1[2]); hn = fsig(z1[3]) * ftanh(cn);
        if (m1){ c10 = cn; h10 = hn; }
        cn = fsig(z1[5]) * c11 + fsig(z1[4]) * ftanh(z1[6]); hn = fsig(z1[7]) * ftanh(cn);
        if (m1){ c11 = cn; h11 = hn; }

        // ---- publish h(t): relaxed sc1 stores, drain, barrier, relaxed flag --
        unsigned p0 = (unsigned)f2bf(h00) | ((unsigned)f2bf(h01) << 16);
        unsigned p1 = (unsigned)f2bf(h10) | ((unsigned)f2bf(h11) << 16);
        size_t dblk = ((size_t)(LAYER == 2 ? (t & 7) : t) * 4 + g) * 2048;
        ast(hout + dblk + woff0,      p0);
        ast(hout + dblk + woff0 + 32, p1);
        asm volatile("s_waitcnt vmcnt(0)" ::: "memory");   // data acked at coherence pt
        __syncthreads();                                   // all waves drained
        if (tid == 0) ast((unsigned*)(pF + n), (unsigned)(t + 1));  // h(t)/x(t) ready
    }

    if (LAYER == 2){
        const int colb = n * 64 + w * 16 + up * 2;
        hfinal[(size_t)myseq0 * 256 + colb]     = h00;
        hfinal[(size_t)myseq0 * 256 + colb + 1] = h01;
        hfinal[(size_t)myseq1 * 256 + colb]     = h10;
        hfinal[(size_t)myseq1 * 256 + colb + 1] = h11;
    }
}

__global__ __launch_bounds__(256, 1) void scan3_kernel(
    const unsigned int* xb, unsigned int* h0, unsigned int* h1, unsigned int* h2,
    const float* W0, const float* U0, const float* b0,
    const float* W1, const float* U1, const float* b1,
    const float* W2, const float* U2, const float* b2,
    const unsigned int* mb, int* flags, float* hfinal)
{
    const int layer = blockIdx.x >> 4;
    if (layer == 0)      scan_layer<0>(xb, h0, W0, U0, b0, mb, nullptr, flags);
    else if (layer == 1) scan_layer<1>(h0, h1, W1, U1, b1, mb, nullptr, flags);
    else                 scan_layer<2>(h1, h2, W2, U2, b2, mb, hfinal,  flags);
}

// ---------------------------------------------------------------------------
__global__ void final_kernel(const float* __restrict__ hfinal, const float* __restrict__ dw,
                             const float* __restrict__ db, float* __restrict__ out){
    const int b = threadIdx.x >> 3, j = threadIdx.x & 7;
    const float* ha = hfinal + (size_t)(2 * b) * 256;
    const float* hb = ha + 256;
    float s = 0.0f;
    for (int d = j; d < 256; d += 8){ float df = ha[d] - hb[d]; s += df * df; }
    #pragma unroll
    for (int off = 4; off; off >>= 1) s += __shfl_xor(s, off, 8);
    if (j == 0){
        float dist = sqrtf(s);
        dist = fminf(fmaxf(dist, 1e-7f), 1e7f);
        out[b] = fsig(dist * dw[0] + db[0]);
    }
}

// ---------------------------------------------------------------------------
extern "C" void kernel_launch(void* const* d_in, const int* in_sizes, int n_in,
                              void* d_out, int out_size, void* d_ws, size_t ws_size,
                              hipStream_t stream){
    const float* x  = (const float*)d_in[0];
    const float* W0 = (const float*)d_in[1];
    const float* U0 = (const float*)d_in[2];
    const float* b0 = (const float*)d_in[3];
    const float* W1 = (const float*)d_in[4];
    const float* U1 = (const float*)d_in[5];
    const float* b1 = (const float*)d_in[6];
    const float* W2 = (const float*)d_in[7];
    const float* U2 = (const float*)d_in[8];
    const float* b2 = (const float*)d_in[9];
    const float* dw = (const float*)d_in[10];
    const float* db = (const float*)d_in[11];

    char* ws = (char*)d_ws;
    unsigned int* xb     = (unsigned int*)(ws);                    // 16 MB
    unsigned int* h0     = (unsigned int*)(ws + 16777216ull);      // 32 MB
    unsigned int* h1     = (unsigned int*)(ws + 50331648ull);      // 32 MB
    unsigned int* h2     = (unsigned int*)(ws + 83886080ull);      // 256 KB ring
    unsigned int* mb     = (unsigned int*)(ws + 84148224ull);      // 8 KB
    int*          flags  = (int*)(ws + 84156416ull);               // 256 ints
    float*        hfinal = (float*)(ws + 84157440ull);             // 64 KB
    float*        out    = (float*)d_out;

    prep_kernel<<<dim3(64, 16), 64, 0, stream>>>(x, xb, mb, flags);
    scan3_kernel<<<48, 256, 0, stream>>>(xb, h0, h1, h2,
                                         W0, U0, b0, W1, U1, b1, W2, U2, b2,
                                         mb, flags, hfinal);
    final_kernel<<<1, 256, 0, stream>>>(hfinal, dw, db, out);
}